// Round 4
// baseline (66.725 us; speedup 1.0000x reference)
//
#include <hip/hip_runtime.h>
#include <cstring>

typedef unsigned int u32;
typedef unsigned long long u64;

#define NEVENTS 268
#define MAXSP_INLINE 320

// ---------------- Threefry2x32-20 (exact JAX semantics, host+device) --------
__host__ __device__ __forceinline__ u32 rotl32(u32 v, int d) {
#if defined(__HIP_DEVICE_COMPILE__)
  // force single-instruction rotate: alignbit(v,v,32-d) == rotl(v,d)
  return __builtin_amdgcn_alignbit(v, v, (u32)(32 - d));
#else
  return (v << d) | (v >> (32 - d));
#endif
}

__host__ __device__ __forceinline__ void tf(u32 k0, u32 k1, u32 x0, u32 x1, u32& o0, u32& o1) {
  u32 ks2 = k0 ^ k1 ^ 0x1BD11BDAu;
  x0 += k0; x1 += k1;
#define RND(r) { x0 += x1; x1 = rotl32(x1, r); x1 ^= x0; }
  RND(13) RND(15) RND(26) RND(6)
  x0 += k1;  x1 += ks2 + 1u;
  RND(17) RND(29) RND(16) RND(24)
  x0 += ks2; x1 += k0 + 2u;
  RND(13) RND(15) RND(26) RND(6)
  x0 += k0;  x1 += k1 + 3u;
  RND(17) RND(29) RND(16) RND(24)
  x0 += k1;  x1 += ks2 + 4u;
  RND(13) RND(15) RND(26) RND(6)
  x0 += ks2; x1 += k0 + 5u;
#undef RND
  o0 = x0; o1 = x1;
}

__host__ __device__ __forceinline__ u32 tfx(u32 k0, u32 k1, u32 lo) {
  u32 a, b; tf(k0, k1, 0u, lo, a, b); return a ^ b;
}
__host__ __device__ __forceinline__ void tfsplit(u32 k0, u32 k1, u32 j, u32& c0, u32& c1) {
  tf(k0, k1, 0u, j, c0, c1);
}
// JAX randint modular combine (uint32 wraparound algebra, exactly as lax)
__host__ __device__ __forceinline__ u32 combine(u32 hi, u32 lo, u32 span) {
  u32 m = 65536u % span;
  m = (m * m) % span;                 // uint32 wraparound mul == lax.mul
  return ((hi % span) * m + (lo % span)) % span;
}
static u32 h_randint(u32 k0, u32 k1, u32 span) {
  u32 h0, h1, l0, l1;
  tfsplit(k0, k1, 0u, h0, h1);
  tfsplit(k0, k1, 1u, l0, l1);
  return combine(tfx(h0, h1, 0u), tfx(l0, l1, 0u), span);
}

// ---------------- host digest of the 268-event stream -----------------------
struct HostDigest {
  int lastwc;
  u32 wk0, wk1, pin;
  int ns;
  u32 sidx[NEVENTS * 8];
  u32 smsk[NEVENTS * 8];
};

static void addSparse(HostDigest& D, u32 idx, u32 msk) {
  if (!msk) return;
  for (int j = 0; j < D.ns; j++)
    if (D.sidx[j] == idx) { D.smsk[j] ^= msk; return; }
  D.sidx[D.ns] = idx; D.smsk[D.ns] = msk; D.ns++;
}

static void computeDigest(u32 n, HostDigest& D) {
  int types[NEVENTS]; u32 A[NEVENTS], M0[NEVENTS], M1[NEVENTS];
  const float pc0 = 0.7398f;
  const float pc1 = pc0 + 0.2256f;
  const float pc2 = pc1 + 0.009f;
  const float pc3 = pc2 + 0.0223f;
  const float pc4 = pc3 + 0.0019f;

  for (int e = 0; e < NEVENTS; e++) {
    u32 e0, e1; tf(0u, 42u, 0u, (u32)e, e0, e1);
    u32 t0, t1, a0, a1;
    tfsplit(e0, e1, 0u, t0, t1);
    tfsplit(e0, e1, 1u, a0, a1);
    u32 ub = tfx(t0, t1, 0u);
    float u; u32 fb = (ub >> 9) | 0x3f800000u; memcpy(&u, &fb, 4); u -= 1.0f;
    float r = pc4 * (1.0f - u);
    int t = 0;
    if (pc0 < r) t = 1;
    if (pc1 < r) t = 2;
    if (pc2 < r) t = 3;
    if (pc3 < r) t = 4;
    types[e] = t; A[e] = 0; M0[e] = 0; M1[e] = 0;

    if (t == 0) {                       // single_bit
      u32 k1a, k1b, k2a, k2b;
      tfsplit(a0, a1, 0u, k1a, k1b);
      tfsplit(a0, a1, 1u, k2a, k2b);
      A[e] = h_randint(k1a, k1b, n);
      M0[e] = 1u << h_randint(k2a, k2b, 8u);
    } else if (t == 1) {                // byte_aligned
      u32 k1a, k1b, k2a, k2b, k3a, k3b;
      tfsplit(a0, a1, 0u, k1a, k1b);
      tfsplit(a0, a1, 1u, k2a, k2b);
      tfsplit(a0, a1, 2u, k3a, k3b);
      A[e] = h_randint(k1a, k1b, n);
      u32 nb = 2u + h_randint(k2a, k2b, 7u);
      u32 sk0, sk1; tfsplit(k3a, k3b, 1u, sk0, sk1);
      u32 keys[8], vals[8];
      for (int j = 0; j < 8; j++) { keys[j] = tfx(sk0, sk1, (u32)j); vals[j] = (u32)j; }
      for (int p = 1; p < 8; p++) {     // stable ascending (sort_key_val)
        u32 kk = keys[p], vv = vals[p]; int q = p - 1;
        while (q >= 0 && keys[q] > kk) { keys[q+1] = keys[q]; vals[q+1] = vals[q]; q--; }
        keys[q+1] = kk; vals[q+1] = vv;
      }
      u32 mask = 0;
      for (u32 j = 0; j < nb; j++) mask |= (1u << vals[j]);
      M0[e] = mask;
    } else if (t == 2) {                // non_byte: 8-byte segment bit parity
      u32 k1a, k1b, k2a, k2b, k3a, k3b;
      tfsplit(a0, a1, 0u, k1a, k1b);
      tfsplit(a0, a1, 1u, k2a, k2b);
      tfsplit(a0, a1, 2u, k3a, k3b);
      A[e] = h_randint(k1a, k1b, n - 7u);
      u32 nb = 2u + h_randint(k2a, k2b, 63u);
      u32 l0, l1; tfsplit(k3a, k3b, 1u, l0, l1);   // span 64 -> lower-bits only
      u64 par = 0ull;
      for (u32 j = 0; j < nb; j++) par ^= (1ull << (tfx(l0, l1, j) & 63u));
      M0[e] = (u32)(par & 0xffffffffull); M1[e] = (u32)(par >> 32);
    } else if (t == 3) {                // whole_chip: keep lower-bits subkey
      u32 l0, l1; tfsplit(a0, a1, 1u, l0, l1);
      M0[e] = l0; M1[e] = l1;
    } else {                            // pin
      M0[e] = 1u << h_randint(a0, a1, 8u);
    }
  }

  int lw = -1;
  for (int e = 0; e < NEVENTS; e++) if (types[e] == 3) lw = e;
  D.lastwc = lw;
  D.wk0 = (lw >= 0) ? M0[lw] : 0u;
  D.wk1 = (lw >= 0) ? M1[lw] : 0u;
  D.pin = 0u; D.ns = 0;
  for (int e = lw + 1; e < NEVENTS; e++) {
    int t = types[e];
    if (t == 0 || t == 1) addSparse(D, A[e], M0[e]);
    else if (t == 2) {
      u64 par = ((u64)M1[e] << 32) | (u64)M0[e];
      for (int q = 0; q < 8; q++) addSparse(D, A[e] + (u32)q, (u32)((par >> (8*q)) & 255ull));
    } else if (t == 4) D.pin ^= M0[e];
  }
}

// ---------------- inline sparse list (kernarg) ------------------------------
struct SpList { u32 cnt; u32 idx[MAXSP_INLINE]; u32 msk[MAXSP_INLINE]; };

// apply sparse entries hitting this thread's 8-element window [base, base+8)
// NOTE: all vb indices compile-time constant (runtime index would spill to scratch)
__device__ __forceinline__ void applySparse(const SpList& sp, u32 base, u32 blkLo, u32 (&vb)[8]) {
  u32 blkHi = blkLo + 2048u;
  for (u32 s = 0; s < sp.cnt; s++) {        // uniform SGPR loop over kernarg
    u32 si = sp.idx[s];
    if (si >= blkLo && si < blkHi) {        // uniform: ~40 blocks of 16384 enter
      u32 m = sp.msk[s];
      if (si == base + 0u) vb[0] ^= m;
      if (si == base + 1u) vb[1] ^= m;
      if (si == base + 2u) vb[2] ^= m;
      if (si == base + 3u) vb[3] ^= m;
      if (si == base + 4u) vb[4] ^= m;
      if (si == base + 5u) vb[5] ^= m;
      if (si == base + 6u) vb[6] ^= m;
      if (si == base + 7u) vb[7] ^= m;
    }
  }
}

// ---------------- kernel: whole-chip regen ^ pin ^ sparse, fused ------------
__global__ void __launch_bounds__(256) buildGen(int* __restrict__ out, u32 n,
                                                u32 k0, u32 k1, u32 pin, SpList sp) {
  u32 blkLo = blockIdx.x * 2048u;
  u32 base = blkLo + threadIdx.x * 8u;
  if (base >= n) return;
  if (base + 8u <= n) {
    u32 vb[8];
#pragma unroll
    for (int j = 0; j < 8; j++)
      vb[j] = (tfx(k0, k1, base + (u32)j) ^ pin) & 255u;
    applySparse(sp, base, blkLo, vb);
    int4 v0, v1;
    v0.x = (int)vb[0]; v0.y = (int)vb[1]; v0.z = (int)vb[2]; v0.w = (int)vb[3];
    v1.x = (int)vb[4]; v1.y = (int)vb[5]; v1.z = (int)vb[6]; v1.w = (int)vb[7];
    *reinterpret_cast<int4*>(out + base)      = v0;
    *reinterpret_cast<int4*>(out + base + 4u) = v1;
  } else {
    for (u32 j = base; j < n; j++) {
      u32 v = (tfx(k0, k1, j) ^ pin) & 255u;
      for (u32 s = 0; s < sp.cnt; s++) if (sp.idx[s] == j) v ^= sp.msk[s];
      out[j] = (int)v;
    }
  }
}

// ---------------- kernel: copy x ^ pin ^ sparse, fused ----------------------
__global__ void __launch_bounds__(256) buildCopy(const int* __restrict__ x,
                                                 int* __restrict__ out, u32 n,
                                                 u32 pin, SpList sp) {
  u32 blkLo = blockIdx.x * 2048u;
  u32 base = blkLo + threadIdx.x * 8u;
  if (base >= n) return;
  if (base + 8u <= n) {
    int4 a0 = *reinterpret_cast<const int4*>(x + base);
    int4 a1 = *reinterpret_cast<const int4*>(x + base + 4);
    u32 vb[8];
    vb[0] = (u32)a0.x ^ pin; vb[1] = (u32)a0.y ^ pin; vb[2] = (u32)a0.z ^ pin; vb[3] = (u32)a0.w ^ pin;
    vb[4] = (u32)a1.x ^ pin; vb[5] = (u32)a1.y ^ pin; vb[6] = (u32)a1.z ^ pin; vb[7] = (u32)a1.w ^ pin;
    applySparse(sp, base, blkLo, vb);
    int4 v0, v1;
    v0.x = (int)vb[0]; v0.y = (int)vb[1]; v0.z = (int)vb[2]; v0.w = (int)vb[3];
    v1.x = (int)vb[4]; v1.y = (int)vb[5]; v1.z = (int)vb[6]; v1.w = (int)vb[7];
    *reinterpret_cast<int4*>(out + base)      = v0;
    *reinterpret_cast<int4*>(out + base + 4u) = v1;
  } else {
    for (u32 j = base; j < n; j++) {
      u32 v = (u32)x[j] ^ pin;
      for (u32 s = 0; s < sp.cnt; s++) if (sp.idx[s] == j) v ^= sp.msk[s];
      out[j] = (int)v;
    }
  }
}

// ---------------- fallback: residual sparse entries (ns > MAXSP_INLINE) -----
struct SpChunk { u32 cnt; u32 idx[256]; u32 msk[256]; };
__global__ void __launch_bounds__(256) sparseK(int* __restrict__ out, SpChunk c) {
  u32 j = threadIdx.x;
  if (j < c.cnt) out[c.idx[j]] ^= (int)c.msk[j];   // host-deduped: no atomics
}

extern "C" void kernel_launch(void* const* d_in, const int* in_sizes, int n_in,
                              void* d_out, int out_size, void* d_ws, size_t ws_size,
                              hipStream_t stream) {
  const int* x = (const int*)d_in[0];
  int* out = (int*)d_out;
  u32 n = (u32)in_sizes[0];

  HostDigest D;
  computeDigest(n, D);   // pure CPU integer arithmetic, deterministic

  SpList sp;
  int inl = D.ns < MAXSP_INLINE ? D.ns : MAXSP_INLINE;
  sp.cnt = (u32)inl;
  for (int j = 0; j < inl; j++) { sp.idx[j] = D.sidx[j]; sp.msk[j] = D.smsk[j]; }
  for (int j = inl; j < MAXSP_INLINE; j++) { sp.idx[j] = 0u; sp.msk[j] = 0u; }

  u32 blocks = (n + 2047u) / 2048u;   // 8 elems/thread, 256 threads/block
  if (D.lastwc >= 0)
    buildGen<<<blocks, 256, 0, stream>>>(out, n, D.wk0, D.wk1, D.pin, sp);
  else
    buildCopy<<<blocks, 256, 0, stream>>>(x, out, n, D.pin, sp);

  for (int off = inl; off < D.ns; off += 256) {   // realistically never taken
    SpChunk c;
    c.cnt = (u32)((D.ns - off) < 256 ? (D.ns - off) : 256);
    for (u32 j = 0; j < c.cnt; j++) { c.idx[j] = D.sidx[off + j]; c.msk[j] = D.smsk[off + j]; }
    sparseK<<<1, 256, 0, stream>>>(out, c);
  }
}